// Round 5
// baseline (76.009 us; speedup 1.0000x reference)
//
#include <hip/hip_runtime.h>
#include <hip/hip_bf16.h>

typedef float f32x4 __attribute__((ext_vector_type(4)));
typedef float f32x2 __attribute__((ext_vector_type(2)));
typedef short s16x8 __attribute__((ext_vector_type(8)));
typedef short s16x4 __attribute__((ext_vector_type(4)));

#define NB  4
#define NTQ 128
#define NTK 512
#define NH  1024

__device__ __forceinline__ unsigned short f2bf(float x) {
    unsigned u = __builtin_bit_cast(unsigned, x);
    u += 0x7FFFu + ((u >> 16) & 1u);          // round-to-nearest-even
    return (unsigned short)(u >> 16);
}

#define K2E  2.8853900817779268f   // 2*log2(e): exp2(K2E*x) = e^{2x}

// async global->LDS 16B: linear LDS dest (wave base + lane*16), per-lane global src
#define GLD16(gp, lp) __builtin_amdgcn_global_load_lds( \
    (const __attribute__((address_space(1))) unsigned int*)(gp), \
    (__attribute__((address_space(3))) unsigned int*)(lp), 16, 0, 0)

// ---------------------------------------------------------------------------
// prep: bf16 convert Q,K; transpose-convert Wq,Wk -> [n][k]; value -> [b][d][k]
// blocks: [0,512) Q | [512,2560) K | [2560,3584) Wq | [3584,4608) Wk | [4608,6656) value
__global__ __launch_bounds__(256) void prep_kernel(
    const float* __restrict__ Q, const float* __restrict__ K,
    const float* __restrict__ Wq, const float* __restrict__ Wk,
    const float* __restrict__ value,
    short* __restrict__ Qb, short* __restrict__ Kb,
    short* __restrict__ WqT, short* __restrict__ WkT, short* __restrict__ valT)
{
    const int t = threadIdx.x, bx = blockIdx.x;
    if (bx < 2560) {
        const float* src; short* dst; size_t off;
        if (bx < 512) { src = Q; dst = Qb; off = (size_t)bx * 1024 + t * 4; }
        else          { src = K; dst = Kb; off = (size_t)(bx - 512) * 1024 + t * 4; }
        const float4 vv = *(const float4*)(src + off);
        s16x4 o = { (short)f2bf(vv.x), (short)f2bf(vv.y),
                    (short)f2bf(vv.z), (short)f2bf(vv.w) };
        *(s16x4*)(dst + off) = o;
        return;
    }
    __shared__ float tile[32][33];
    const float* src; short* dst; int R, C, r0, c0;
    if (bx < 3584)      { const int i = bx - 2560; src = Wq; dst = WqT; C = 1024; R = 1024; r0 = (i >> 5) * 32; c0 = (i & 31) * 32; }
    else if (bx < 4608) { const int i = bx - 3584; src = Wk; dst = WkT; C = 1024; R = 1024; r0 = (i >> 5) * 32; c0 = (i & 31) * 32; }
    else {
        const int i = bx - 4608, b = i >> 9, rr = i & 511;
        src = value + (size_t)b * 512 * 1024; dst = valT + (size_t)b * 1024 * 512;
        C = 1024; R = 512; r0 = (rr >> 5) * 32; c0 = (rr & 31) * 32;
    }
    const int lr = t >> 3, lc = (t & 7) * 4;
    {
        const float4 vv = *(const float4*)(src + (size_t)(r0 + lr) * C + c0 + lc);
        tile[lr][lc + 0] = vv.x; tile[lr][lc + 1] = vv.y;
        tile[lr][lc + 2] = vv.z; tile[lr][lc + 3] = vv.w;
    }
    __syncthreads();
    s16x4 o = { (short)f2bf(tile[lc + 0][lr]), (short)f2bf(tile[lc + 1][lr]),
                (short)f2bf(tile[lc + 2][lr]), (short)f2bf(tile[lc + 3][lr]) };
    *(s16x4*)(dst + (size_t)(c0 + lr) * R + r0 + lc) = o;
}

// ---------------------------------------------------------------------------
// main GEMMs with epilogue exp: swz blocks [0,64): Ea = exp(2*(Q@Wq+bq));
// [64,320): EbT[b][h][k] = exp(2*(K@Wk)) transposed.
// 128m x 64n tile, BK=64, dbuf LDS via global_load_lds, XOR-swizzled (rule #21),
// XCD-chunked blockIdx swizzle (320 % 8 == 0).
__global__ __launch_bounds__(256) void mm_kernel(
    const short* __restrict__ Qb, const short* __restrict__ Kb,
    const short* __restrict__ WqT, const short* __restrict__ WkT,
    const float* __restrict__ bq,
    float* __restrict__ Ea_out, float* __restrict__ EbT)
{
    __shared__ short ldsA[2][128][64];   // 32 KB
    __shared__ short ldsB[2][64][64];    // 16 KB
    const int t = threadIdx.x;
    const int bx0 = blockIdx.x;
    const int bx = (bx0 & 7) * 40 + (bx0 >> 3);   // XCD-chunked swizzle
    const bool g1 = bx < 64;
    const short *A, *B; int m0, n0;
    if (g1) { A = Qb; B = WqT; m0 = (bx >> 4) * 128; n0 = (bx & 15) * 64; }
    else    { const int i = bx - 64; A = Kb; B = WkT; m0 = (i >> 4) * 128; n0 = (i & 15) * 64; }
    A += (size_t)m0 * 1024; B += (size_t)n0 * 1024;

    f32x4 acc[4][2];
    #pragma unroll
    for (int i = 0; i < 4; ++i)
        #pragma unroll
        for (int j = 0; j < 2; ++j) acc[i][j] = f32x4{0.f, 0.f, 0.f, 0.f};

    const int lane = t & 63, wid = t >> 6;
    const int wr = wid >> 1, wc = wid & 1;          // waves 2x2 over (64m,32n)
    const int fr = lane & 15, fko = (lane >> 4) * 16;   // byte offset in 128B row

    #define STAGE_MM(buf, k0) do {                                              \
        _Pragma("unroll")                                                       \
        for (int it = 0; it < 4; ++it) {                                        \
            const int idx = it * 256 + t;                                       \
            const int row = idx >> 3, c16 = idx & 7;                            \
            const int sc = c16 ^ (row & 7);                                     \
            GLD16(A + (size_t)row * 1024 + (k0) + sc * 8,                       \
                  &ldsA[buf][0][0] + idx * 8);                                  \
        }                                                                       \
        _Pragma("unroll")                                                       \
        for (int it = 0; it < 2; ++it) {                                        \
            const int idx = it * 256 + t;                                       \
            const int row = idx >> 3, c16 = idx & 7;                            \
            const int sc = c16 ^ (row & 7);                                     \
            GLD16(B + (size_t)row * 1024 + (k0) + sc * 8,                       \
                  &ldsB[buf][0][0] + idx * 8);                                  \
        }                                                                       \
    } while (0)

    #define COMPUTE_MM(buf) do {                                                \
        _Pragma("unroll")                                                       \
        for (int kk = 0; kk < 2; ++kk) {                                        \
            s16x8 af[4], bfv[2];                                                \
            _Pragma("unroll")                                                   \
            for (int i = 0; i < 4; ++i) {                                       \
                const int rowA = wr * 64 + i * 16 + fr;                         \
                int offA = rowA * 128 + kk * 64 + fko; offA ^= (rowA & 7) << 4; \
                af[i] = *(const s16x8*)((const char*)&ldsA[buf][0][0] + offA);  \
            }                                                                   \
            _Pragma("unroll")                                                   \
            for (int ni = 0; ni < 2; ++ni) {                                    \
                const int rowB = wc * 32 + ni * 16 + fr;                        \
                int offB = rowB * 128 + kk * 64 + fko; offB ^= (rowB & 7) << 4; \
                bfv[ni] = *(const s16x8*)((const char*)&ldsB[buf][0][0] + offB);\
            }                                                                   \
            _Pragma("unroll")                                                   \
            for (int mi = 0; mi < 4; ++mi)                                      \
                _Pragma("unroll")                                               \
                for (int ni = 0; ni < 2; ++ni)                                  \
                    acc[mi][ni] = __builtin_amdgcn_mfma_f32_16x16x32_bf16(      \
                                      af[mi], bfv[ni], acc[mi][ni], 0, 0, 0);   \
        }                                                                       \
    } while (0)

    STAGE_MM(0, 0);
    __syncthreads();
    int cur = 0;
    for (int s = 0; s < 15; ++s) {
        STAGE_MM(cur ^ 1, (s + 1) * 64);
        COMPUTE_MM(cur);
        __syncthreads();
        cur ^= 1;
    }
    COMPUTE_MM(cur);

    // D layout: col = lane&15, row = (lane>>4)*4 + reg
    const int row0 = (lane >> 4) * 4;
    if (g1) {
        #pragma unroll
        for (int ni = 0; ni < 2; ++ni) {
            const int n = n0 + wc * 32 + ni * 16 + fr;
            const float bias = bq[n];
            #pragma unroll
            for (int mi = 0; mi < 4; ++mi) {
                const int m = m0 + wr * 64 + mi * 16 + row0;
                #pragma unroll
                for (int j = 0; j < 4; ++j)
                    Ea_out[(size_t)(m + j) * 1024 + n] =
                        __builtin_amdgcn_exp2f(K2E * (acc[mi][ni][j] + bias));
            }
        }
    } else {
        #pragma unroll
        for (int mi = 0; mi < 4; ++mi) {
            const int m = m0 + wr * 64 + mi * 16 + row0;
            const int b = m >> 9, kk = m & 511;
            #pragma unroll
            for (int ni = 0; ni < 2; ++ni) {
                const int n = n0 + wc * 32 + ni * 16 + fr;
                f32x4 ev;
                #pragma unroll
                for (int j = 0; j < 4; ++j)
                    ev[j] = __builtin_amdgcn_exp2f(K2E * acc[mi][ni][j]);
                *(f32x4*)&EbT[((size_t)b * 1024 + n) * 512 + kk] = ev;
            }
        }
    }
    #undef STAGE_MM
    #undef COMPUTE_MM
}

// ---------------------------------------------------------------------------
// scores: partial[bqi][hc][k] = sum_{h in chunk} v[h]*rcp(1+Ea[bqi][h]*Eb[b][h][k])
// grid: (b*16+q8)*8 + hc; q-tile 8, h-chunk 128; 512 threads = k
// packed f32x2 math -> v_pk_fma_f32; Ea via 2x ds_read_b128 broadcast
__global__ __launch_bounds__(512) void scores_partial(
    const float* __restrict__ EbT, const float* __restrict__ Ea,
    const float* __restrict__ v, float* __restrict__ partial)
{
    __shared__ float4 s_ea4[128][2];
    __shared__ float  s_v[128];
    const int t = threadIdx.x, bx = blockIdx.x;
    const int hc = bx & 7, bq8 = bx >> 3;
    const int b = bq8 >> 4, q8 = bq8 & 15;
    const int bq0 = b * 128 + q8 * 8, h0 = hc * 128;

    if (t < 128) {
        const int h = h0 + t;
        s_ea4[t][0] = make_float4(Ea[(size_t)(bq0 + 0) * 1024 + h],
                                  Ea[(size_t)(bq0 + 1) * 1024 + h],
                                  Ea[(size_t)(bq0 + 2) * 1024 + h],
                                  Ea[(size_t)(bq0 + 3) * 1024 + h]);
        s_ea4[t][1] = make_float4(Ea[(size_t)(bq0 + 4) * 1024 + h],
                                  Ea[(size_t)(bq0 + 5) * 1024 + h],
                                  Ea[(size_t)(bq0 + 6) * 1024 + h],
                                  Ea[(size_t)(bq0 + 7) * 1024 + h]);
        s_v[t] = v[h];
    }
    __syncthreads();

    const float* up = EbT + ((size_t)b * 1024 + h0) * 512 + t;
    f32x2 a0 = {0.f, 0.f}, a1 = {0.f, 0.f}, a2 = {0.f, 0.f}, a3 = {0.f, 0.f};
    #pragma unroll 4
    for (int hh = 0; hh < 128; ++hh) {
        const float  eb = up[(size_t)hh * 512];   // coalesced across lanes
        const float4 e0 = s_ea4[hh][0];           // ds_read_b128 broadcast
        const float4 e1 = s_ea4[hh][1];
        const float  vv = s_v[hh];
        f32x2 p0 = f32x2{e0.x, e0.y} * eb + 1.0f;
        f32x2 p1 = f32x2{e0.z, e0.w} * eb + 1.0f;
        f32x2 p2 = f32x2{e1.x, e1.y} * eb + 1.0f;
        f32x2 p3 = f32x2{e1.z, e1.w} * eb + 1.0f;
        f32x2 r0 = {__builtin_amdgcn_rcpf(p0.x), __builtin_amdgcn_rcpf(p0.y)};
        f32x2 r1 = {__builtin_amdgcn_rcpf(p1.x), __builtin_amdgcn_rcpf(p1.y)};
        f32x2 r2 = {__builtin_amdgcn_rcpf(p2.x), __builtin_amdgcn_rcpf(p2.y)};
        f32x2 r3 = {__builtin_amdgcn_rcpf(p3.x), __builtin_amdgcn_rcpf(p3.y)};
        a0 += r0 * vv;
        a1 += r1 * vv;
        a2 += r2 * vv;
        a3 += r3 * vv;
    }
    partial[((size_t)(bq0 + 0) * 8 + hc) * 512 + t] = a0.x;
    partial[((size_t)(bq0 + 1) * 8 + hc) * 512 + t] = a0.y;
    partial[((size_t)(bq0 + 2) * 8 + hc) * 512 + t] = a1.x;
    partial[((size_t)(bq0 + 3) * 8 + hc) * 512 + t] = a1.y;
    partial[((size_t)(bq0 + 4) * 8 + hc) * 512 + t] = a2.x;
    partial[((size_t)(bq0 + 5) * 8 + hc) * 512 + t] = a2.y;
    partial[((size_t)(bq0 + 6) * 8 + hc) * 512 + t] = a3.x;
    partial[((size_t)(bq0 + 7) * 8 + hc) * 512 + t] = a3.y;
}

// softmax over k of -2*sum_hc partial; writes f32 attn (output) + bf16 copy (for PV)
__global__ __launch_bounds__(512) void softmax_kernel(
    const float* __restrict__ partial, float* __restrict__ attn_out,
    short* __restrict__ attnb)
{
    __shared__ float s_red[16];
    const int t = threadIdx.x, bqi = blockIdx.x;
    const float* p = partial + (size_t)bqi * 4096;
    float zs = 0.f;
    #pragma unroll
    for (int j = 0; j < 8; ++j) zs += p[j * 512 + t];
    const float z = -2.0f * zs;

    const int lane = t & 63, wid = t >> 6;
    float m = z;
    #pragma unroll
    for (int off = 32; off > 0; off >>= 1)
        m = fmaxf(m, __shfl_xor(m, off, 64));
    if (lane == 0) s_red[wid] = m;
    __syncthreads();
    if (t < 64) {
        float mm = (t < 8) ? s_red[t] : -3.0e38f;
        #pragma unroll
        for (int off = 4; off > 0; off >>= 1)
            mm = fmaxf(mm, __shfl_xor(mm, off, 64));
        if (t == 0) s_red[8] = mm;
    }
    __syncthreads();
    const float pr = __expf(z - s_red[8]);
    float s = pr;
    #pragma unroll
    for (int off = 32; off > 0; off >>= 1)
        s += __shfl_xor(s, off, 64);
    if (lane == 0) s_red[wid] = s;
    __syncthreads();
    if (t < 64) {
        float ss = (t < 8) ? s_red[t] : 0.f;
        #pragma unroll
        for (int off = 4; off > 0; off >>= 1)
            ss += __shfl_xor(ss, off, 64);
        if (t == 0) s_red[9] = ss;
    }
    __syncthreads();
    const float attn = pr * (1.0f / s_red[9]);
    attn_out[(size_t)bqi * 512 + t] = attn;
    attnb[(size_t)bqi * 512 + t] = (short)f2bf(attn);
}

// ---------------------------------------------------------------------------
// PV GEMM: outh[b][128][1024] = attnb[b][128][512] @ valT[b][1024][512]^T
// 128m x 64n tile, K=512 (8 steps); grid b*16+nt = 64 blocks
__global__ __launch_bounds__(256) void pv_gemm(
    const short* __restrict__ attnb, const short* __restrict__ valT,
    float* __restrict__ outh)
{
    __shared__ short ldsA[2][128][64];
    __shared__ short ldsB[2][64][64];
    const int t = threadIdx.x, bx = blockIdx.x;
    const int b = bx >> 4, nt = bx & 15;
    const int n0 = nt * 64;
    const short* A = attnb + (size_t)b * 128 * 512;                    // [128][512]
    const short* B = valT + (size_t)b * 1024 * 512 + (size_t)n0 * 512; // [64][512] tile

    f32x4 acc[4][2];
    #pragma unroll
    for (int i = 0; i < 4; ++i)
        #pragma unroll
        for (int j = 0; j < 2; ++j) acc[i][j] = f32x4{0.f, 0.f, 0.f, 0.f};

    const int lane = t & 63, wid = t >> 6;
    const int wr = wid >> 1, wc = wid & 1;
    const int fr = lane & 15, fko = (lane >> 4) * 16;

    #define STAGE_PV(buf, k0) do {                                              \
        _Pragma("unroll")                                                       \
        for (int it = 0; it < 4; ++it) {                                        \
            const int idx = it * 256 + t;                                       \
            const int row = idx >> 3, c16 = idx & 7;                            \
            const int sc = c16 ^ (row & 7);                                     \
            GLD16(A + (size_t)row * 512 + (k0) + sc * 8,                        \
                  &ldsA[buf][0][0] + idx * 8);                                  \
        }                                                                       \
        _Pragma("unroll")                                                       \
        for (int it = 0; it < 2; ++it) {                                        \
            const int idx = it * 256 + t;                                       \
            const int row = idx >> 3, c16 = idx & 7;                            \
            const int sc = c16 ^ (row & 7);                                     \
            GLD16(B + (size_t)row * 512 + (k0) + sc * 8,                        \
                  &ldsB[buf][0][0] + idx * 8);                                  \
        }                                                                       \
    } while (0)

    #define COMPUTE_PV(buf) do {                                                \
        _Pragma("unroll")                                                       \
        for (int kk = 0; kk < 2; ++kk) {                                        \
            s16x8 af[4], bfv[2];                                                \
            _Pragma("unroll")                                                   \
            for (int i = 0; i < 4; ++i) {                                       \
                const int rowA = wr * 64 + i * 16 + fr;                         \
                int offA = rowA * 128 + kk * 64 + fko; offA ^= (rowA & 7) << 4; \
                af[i] = *(const s16x8*)((const char*)&ldsA[buf][0][0] + offA);  \
            }                                                                   \
            _Pragma("unroll")                                                   \
            for (int ni = 0; ni < 2; ++ni) {                                    \
                const int rowB = wc * 32 + ni * 16 + fr;                        \
                int offB = rowB * 128 + kk * 64 + fko; offB ^= (rowB & 7) << 4; \
                bfv[ni] = *(const s16x8*)((const char*)&ldsB[buf][0][0] + offB);\
            }                                                                   \
            _Pragma("unroll")                                                   \
            for (int mi = 0; mi < 4; ++mi)                                      \
                _Pragma("unroll")                                               \
                for (int ni = 0; ni < 2; ++ni)                                  \
                    acc[mi][ni] = __builtin_amdgcn_mfma_f32_16x16x32_bf16(      \
                                      af[mi], bfv[ni], acc[mi][ni], 0, 0, 0);   \
        }                                                                       \
    } while (0)

    STAGE_PV(0, 0);
    __syncthreads();
    int cur = 0;
    for (int s = 0; s < 7; ++s) {
        STAGE_PV(cur ^ 1, (s + 1) * 64);
        COMPUTE_PV(cur);
        __syncthreads();
        cur ^= 1;
    }
    COMPUTE_PV(cur);

    const int row0 = (lane >> 4) * 4;
    #pragma unroll
    for (int ni = 0; ni < 2; ++ni) {
        const int n = n0 + wc * 32 + ni * 16 + fr;
        #pragma unroll
        for (int mi = 0; mi < 4; ++mi) {
            const int m = wr * 64 + mi * 16 + row0;
            #pragma unroll
            for (int j = 0; j < 4; ++j)
                outh[(size_t)(b * 128 + m + j) * 1024 + n] = acc[mi][ni][j];
        }
    }
    #undef STAGE_PV
    #undef COMPUTE_PV
}

extern "C" void kernel_launch(void* const* d_in, const int* in_sizes, int n_in,
                              void* d_out, int out_size, void* d_ws, size_t ws_size,
                              hipStream_t stream)
{
    const float* query = (const float*)d_in[0];
    const float* key   = (const float*)d_in[1];
    const float* value = (const float*)d_in[2];
    const float* Wq    = (const float*)d_in[3];
    const float* bq    = (const float*)d_in[4];
    const float* Wk    = (const float*)d_in[5];
    const float* v     = (const float*)d_in[6];
    float* out = (float*)d_out;

    // workspace layout (23.5 MB):
    char* w = (char*)d_ws;
    float* ws_Ea  = (float*)w;                            // 2 MB
    float* ws_EbT = (float*)(w + (2u << 20));             // 8 MB
    char*  reg    = w + (10u << 20);                      // 9 MB shared region
    short* Qb   = (short*)reg;                            //   1 MB
    short* Kb   = (short*)(reg + (1u << 20));             //   4 MB
    short* WqT  = (short*)(reg + (5u << 20));             //   2 MB
    short* WkT  = (short*)(reg + (7u << 20));             //   2 MB
    float* part = (float*)reg;                            //   8 MB (aliases; Qb..WkT dead after mm)
    short* valT  = (short*)(w + (19u << 20));             // 4 MB
    short* attnb = (short*)(w + (23u << 20));             // 0.5 MB

    float* out_h    = out;                                // [512][1024]
    float* out_attn = out + (size_t)NB * NTQ * NH;        // [512][512]

    prep_kernel   <<<dim3(6656), dim3(256), 0, stream>>>(query, key, Wq, Wk, value,
                                                         Qb, Kb, WqT, WkT, valT);
    mm_kernel     <<<dim3(320),  dim3(256), 0, stream>>>(Qb, Kb, WqT, WkT, bq, ws_Ea, ws_EbT);
    scores_partial<<<dim3(512),  dim3(512), 0, stream>>>(ws_EbT, ws_Ea, v, part);
    softmax_kernel<<<dim3(512),  dim3(512), 0, stream>>>(part, out_attn, attnb);
    pv_gemm       <<<dim3(64),   dim3(256), 0, stream>>>(attnb, valT, out_h);
}

// Round 6
// 72.074 us; speedup vs baseline: 1.0546x; 1.0546x over previous
//
#include <hip/hip_runtime.h>
#include <hip/hip_bf16.h>

typedef float f32x4 __attribute__((ext_vector_type(4)));
typedef float f32x2 __attribute__((ext_vector_type(2)));
typedef short s16x8 __attribute__((ext_vector_type(8)));
typedef short s16x4 __attribute__((ext_vector_type(4)));

#define NB  4
#define NTQ 128
#define NTK 512
#define NH  1024

__device__ __forceinline__ unsigned short f2bf(float x) {
    unsigned u = __builtin_bit_cast(unsigned, x);
    u += 0x7FFFu + ((u >> 16) & 1u);          // round-to-nearest-even
    return (unsigned short)(u >> 16);
}

#define K2E  2.8853900817779268f   // 2*log2(e): exp2(K2E*x) = e^{2x}

// async global->LDS 16B: linear LDS dest (wave base + lane*16), per-lane global src
#define GLD16(gp, lp) __builtin_amdgcn_global_load_lds( \
    (const __attribute__((address_space(1))) unsigned int*)(gp), \
    (__attribute__((address_space(3))) unsigned int*)(lp), 16, 0, 0)

// ---------------------------------------------------------------------------
// prep: blocks [0,640): bf16 copy Q|K (float4 coalesced).
// blocks [640,1664): 64x64 transpose-convert tiles: Wq->WqT, Wk->WkT, value->valT.
// All writes 128B-contiguous per 16-lane group.
__global__ __launch_bounds__(256) void prep_kernel(
    const float* __restrict__ Q, const float* __restrict__ K,
    const float* __restrict__ Wq, const float* __restrict__ Wk,
    const float* __restrict__ value,
    short* __restrict__ Qb, short* __restrict__ Kb,
    short* __restrict__ WqT, short* __restrict__ WkT, short* __restrict__ valT)
{
    const int t = threadIdx.x, bx = blockIdx.x;
    if (bx < 640) {   // copy region: blocks [0,128) = Q, [128,640) = K
        const float* src; short* dst; size_t base;
        if (bx < 128) { src = Q; dst = Qb; base = (size_t)bx * 4096; }
        else          { src = K; dst = Kb; base = (size_t)(bx - 128) * 4096; }
        #pragma unroll
        for (int i = 0; i < 4; ++i) {
            const size_t off = base + (size_t)(i * 256 + t) * 4;
            const float4 vv = *(const float4*)(src + off);
            s16x4 o = { (short)f2bf(vv.x), (short)f2bf(vv.y),
                        (short)f2bf(vv.z), (short)f2bf(vv.w) };
            *(s16x4*)(dst + off) = o;
        }
        return;
    }
    // transpose region
    __shared__ float tile[64][65];
    const int i = bx - 640;
    const float* src; short* dst; int Cs, Rs, r0, c0;
    if (i < 256)      { src = Wq; dst = WqT; Cs = 1024; Rs = 1024; r0 = (i >> 4) * 64; c0 = (i & 15) * 64; }
    else if (i < 512) { const int j = i - 256; src = Wk; dst = WkT; Cs = 1024; Rs = 1024; r0 = (j >> 4) * 64; c0 = (j & 15) * 64; }
    else {
        const int j = i - 512, b = j >> 7, ti = j & 127;
        src = value + (size_t)b * 512 * 1024; dst = valT + (size_t)b * 1024 * 512;
        Cs = 1024; Rs = 512; r0 = (ti >> 4) * 64; c0 = (ti & 15) * 64;
    }
    {   // load 64x64 f32 tile, coalesced 256B/row
        const int c = (t & 15) * 4;
        #pragma unroll
        for (int it = 0; it < 4; ++it) {
            const int r = (t >> 4) + it * 16;
            const float4 vv = *(const float4*)(src + (size_t)(r0 + r) * Cs + c0 + c);
            tile[r][c + 0] = vv.x; tile[r][c + 1] = vv.y;
            tile[r][c + 2] = vv.z; tile[r][c + 3] = vv.w;
        }
    }
    __syncthreads();
    {   // write transposed: dst[(c0+c)*Rs + r0 + r..r+3], 128B per 16-lane group
        const int r = (t & 15) * 4;
        #pragma unroll
        for (int it = 0; it < 4; ++it) {
            const int c = (t >> 4) + it * 16;
            s16x4 o = { (short)f2bf(tile[r + 0][c]), (short)f2bf(tile[r + 1][c]),
                        (short)f2bf(tile[r + 2][c]), (short)f2bf(tile[r + 3][c]) };
            *(s16x4*)(dst + (size_t)(c0 + c) * Rs + r0 + r) = o;
        }
    }
}

// ---------------------------------------------------------------------------
// main GEMMs with epilogue exp: swz blocks [0,64): Ea = exp(2*(Q@Wq+bq));
// [64,320): EbT[b][h][k] = exp(2*(K@Wk)) transposed.
// 128m x 64n tile, BK=64, dbuf LDS via global_load_lds, XOR-swizzled (rule #21),
// XCD-chunked blockIdx swizzle (320 % 8 == 0).
__global__ __launch_bounds__(256) void mm_kernel(
    const short* __restrict__ Qb, const short* __restrict__ Kb,
    const short* __restrict__ WqT, const short* __restrict__ WkT,
    const float* __restrict__ bq,
    float* __restrict__ Ea_out, float* __restrict__ EbT)
{
    __shared__ short ldsA[2][128][64];   // 32 KB
    __shared__ short ldsB[2][64][64];    // 16 KB
    const int t = threadIdx.x;
    const int bx0 = blockIdx.x;
    const int bx = (bx0 & 7) * 40 + (bx0 >> 3);   // XCD-chunked swizzle
    const bool g1 = bx < 64;
    const short *A, *B; int m0, n0;
    if (g1) { A = Qb; B = WqT; m0 = (bx >> 4) * 128; n0 = (bx & 15) * 64; }
    else    { const int i = bx - 64; A = Kb; B = WkT; m0 = (i >> 4) * 128; n0 = (i & 15) * 64; }
    A += (size_t)m0 * 1024; B += (size_t)n0 * 1024;

    f32x4 acc[4][2];
    #pragma unroll
    for (int i = 0; i < 4; ++i)
        #pragma unroll
        for (int j = 0; j < 2; ++j) acc[i][j] = f32x4{0.f, 0.f, 0.f, 0.f};

    const int lane = t & 63, wid = t >> 6;
    const int wr = wid >> 1, wc = wid & 1;          // waves 2x2 over (64m,32n)
    const int fr = lane & 15, fko = (lane >> 4) * 16;   // byte offset in 128B row

    #define STAGE_MM(buf, k0) do {                                              \
        _Pragma("unroll")                                                       \
        for (int it = 0; it < 4; ++it) {                                        \
            const int idx = it * 256 + t;                                       \
            const int row = idx >> 3, c16 = idx & 7;                            \
            const int sc = c16 ^ (row & 7);                                     \
            GLD16(A + (size_t)row * 1024 + (k0) + sc * 8,                       \
                  &ldsA[buf][0][0] + idx * 8);                                  \
        }                                                                       \
        _Pragma("unroll")                                                       \
        for (int it = 0; it < 2; ++it) {                                        \
            const int idx = it * 256 + t;                                       \
            const int row = idx >> 3, c16 = idx & 7;                            \
            const int sc = c16 ^ (row & 7);                                     \
            GLD16(B + (size_t)row * 1024 + (k0) + sc * 8,                       \
                  &ldsB[buf][0][0] + idx * 8);                                  \
        }                                                                       \
    } while (0)

    #define COMPUTE_MM(buf) do {                                                \
        _Pragma("unroll")                                                       \
        for (int kk = 0; kk < 2; ++kk) {                                        \
            s16x8 af[4], bfv[2];                                                \
            _Pragma("unroll")                                                   \
            for (int i = 0; i < 4; ++i) {                                       \
                const int rowA = wr * 64 + i * 16 + fr;                         \
                int offA = rowA * 128 + kk * 64 + fko; offA ^= (rowA & 7) << 4; \
                af[i] = *(const s16x8*)((const char*)&ldsA[buf][0][0] + offA);  \
            }                                                                   \
            _Pragma("unroll")                                                   \
            for (int ni = 0; ni < 2; ++ni) {                                    \
                const int rowB = wc * 32 + ni * 16 + fr;                        \
                int offB = rowB * 128 + kk * 64 + fko; offB ^= (rowB & 7) << 4; \
                bfv[ni] = *(const s16x8*)((const char*)&ldsB[buf][0][0] + offB);\
            }                                                                   \
            _Pragma("unroll")                                                   \
            for (int mi = 0; mi < 4; ++mi)                                      \
                _Pragma("unroll")                                               \
                for (int ni = 0; ni < 2; ++ni)                                  \
                    acc[mi][ni] = __builtin_amdgcn_mfma_f32_16x16x32_bf16(      \
                                      af[mi], bfv[ni], acc[mi][ni], 0, 0, 0);   \
        }                                                                       \
    } while (0)

    STAGE_MM(0, 0);
    __syncthreads();
    int cur = 0;
    for (int s = 0; s < 15; ++s) {
        STAGE_MM(cur ^ 1, (s + 1) * 64);
        COMPUTE_MM(cur);
        __syncthreads();
        cur ^= 1;
    }
    COMPUTE_MM(cur);

    // D layout: col = lane&15, row = (lane>>4)*4 + reg
    const int row0 = (lane >> 4) * 4;
    if (g1) {
        #pragma unroll
        for (int ni = 0; ni < 2; ++ni) {
            const int n = n0 + wc * 32 + ni * 16 + fr;
            const float bias = bq[n];
            #pragma unroll
            for (int mi = 0; mi < 4; ++mi) {
                const int m = m0 + wr * 64 + mi * 16 + row0;
                #pragma unroll
                for (int j = 0; j < 4; ++j)
                    Ea_out[(size_t)(m + j) * 1024 + n] =
                        __builtin_amdgcn_exp2f(K2E * (acc[mi][ni][j] + bias));
            }
        }
    } else {
        #pragma unroll
        for (int mi = 0; mi < 4; ++mi) {
            const int m = m0 + wr * 64 + mi * 16 + row0;
            const int b = m >> 9, kk = m & 511;
            #pragma unroll
            for (int ni = 0; ni < 2; ++ni) {
                const int n = n0 + wc * 32 + ni * 16 + fr;
                f32x4 ev;
                #pragma unroll
                for (int j = 0; j < 4; ++j)
                    ev[j] = __builtin_amdgcn_exp2f(K2E * acc[mi][ni][j]);
                *(f32x4*)&EbT[((size_t)b * 1024 + n) * 512 + kk] = ev;
            }
        }
    }
    #undef STAGE_MM
    #undef COMPUTE_MM
}

// ---------------------------------------------------------------------------
// scores: partial[bqi][hc][k] = sum_{h in chunk} v[h]*rcp(1+Ea[bqi][h]*Eb[b][h][k])
// grid: (b*16+q8)*16 + hc = 1024 blocks; q-tile 8, h-chunk 64; 512 threads = k.
// 8192 waves -> 32 waves/CU for latency hiding over the strided EbT loads.
__global__ __launch_bounds__(512) void scores_partial(
    const float* __restrict__ EbT, const float* __restrict__ Ea,
    const float* __restrict__ v, float* __restrict__ partial)
{
    __shared__ float4 s_ea4[64][2];
    __shared__ float  s_v[64];
    const int t = threadIdx.x, bx = blockIdx.x;
    const int hc = bx & 15, bq8 = bx >> 4;
    const int b = bq8 >> 4, q8 = bq8 & 15;
    const int bq0 = b * 128 + q8 * 8, h0 = hc * 64;

    if (t < 64) {
        const int h = h0 + t;
        s_ea4[t][0] = make_float4(Ea[(size_t)(bq0 + 0) * 1024 + h],
                                  Ea[(size_t)(bq0 + 1) * 1024 + h],
                                  Ea[(size_t)(bq0 + 2) * 1024 + h],
                                  Ea[(size_t)(bq0 + 3) * 1024 + h]);
        s_ea4[t][1] = make_float4(Ea[(size_t)(bq0 + 4) * 1024 + h],
                                  Ea[(size_t)(bq0 + 5) * 1024 + h],
                                  Ea[(size_t)(bq0 + 6) * 1024 + h],
                                  Ea[(size_t)(bq0 + 7) * 1024 + h]);
        s_v[t] = v[h];
    }
    __syncthreads();

    const float* up = EbT + ((size_t)b * 1024 + h0) * 512 + t;
    f32x2 a0 = {0.f, 0.f}, a1 = {0.f, 0.f}, a2 = {0.f, 0.f}, a3 = {0.f, 0.f};
    #pragma unroll 4
    for (int hh = 0; hh < 64; ++hh) {
        const float  eb = up[(size_t)hh * 512];   // coalesced across lanes
        const float4 e0 = s_ea4[hh][0];           // LDS broadcast
        const float4 e1 = s_ea4[hh][1];
        const float  vv = s_v[hh];
        f32x2 p0 = f32x2{e0.x, e0.y} * eb + 1.0f;
        f32x2 p1 = f32x2{e0.z, e0.w} * eb + 1.0f;
        f32x2 p2 = f32x2{e1.x, e1.y} * eb + 1.0f;
        f32x2 p3 = f32x2{e1.z, e1.w} * eb + 1.0f;
        f32x2 r0 = {__builtin_amdgcn_rcpf(p0.x), __builtin_amdgcn_rcpf(p0.y)};
        f32x2 r1 = {__builtin_amdgcn_rcpf(p1.x), __builtin_amdgcn_rcpf(p1.y)};
        f32x2 r2 = {__builtin_amdgcn_rcpf(p2.x), __builtin_amdgcn_rcpf(p2.y)};
        f32x2 r3 = {__builtin_amdgcn_rcpf(p3.x), __builtin_amdgcn_rcpf(p3.y)};
        a0 += r0 * vv;
        a1 += r1 * vv;
        a2 += r2 * vv;
        a3 += r3 * vv;
    }
    partial[((size_t)(bq0 + 0) * 16 + hc) * 512 + t] = a0.x;
    partial[((size_t)(bq0 + 1) * 16 + hc) * 512 + t] = a0.y;
    partial[((size_t)(bq0 + 2) * 16 + hc) * 512 + t] = a1.x;
    partial[((size_t)(bq0 + 3) * 16 + hc) * 512 + t] = a1.y;
    partial[((size_t)(bq0 + 4) * 16 + hc) * 512 + t] = a2.x;
    partial[((size_t)(bq0 + 5) * 16 + hc) * 512 + t] = a2.y;
    partial[((size_t)(bq0 + 6) * 16 + hc) * 512 + t] = a3.x;
    partial[((size_t)(bq0 + 7) * 16 + hc) * 512 + t] = a3.y;
}

// softmax over k of -2*sum_hc partial; writes f32 attn (output) + bf16 copy (for PV)
__global__ __launch_bounds__(512) void softmax_kernel(
    const float* __restrict__ partial, float* __restrict__ attn_out,
    short* __restrict__ attnb)
{
    __shared__ float s_red[16];
    const int t = threadIdx.x, bqi = blockIdx.x;
    const float* p = partial + (size_t)bqi * 16 * 512;
    float zs = 0.f;
    #pragma unroll
    for (int j = 0; j < 16; ++j) zs += p[j * 512 + t];
    const float z = -2.0f * zs;

    const int lane = t & 63, wid = t >> 6;
    float m = z;
    #pragma unroll
    for (int off = 32; off > 0; off >>= 1)
        m = fmaxf(m, __shfl_xor(m, off, 64));
    if (lane == 0) s_red[wid] = m;
    __syncthreads();
    if (t < 64) {
        float mm = (t < 8) ? s_red[t] : -3.0e38f;
        #pragma unroll
        for (int off = 4; off > 0; off >>= 1)
            mm = fmaxf(mm, __shfl_xor(mm, off, 64));
        if (t == 0) s_red[8] = mm;
    }
    __syncthreads();
    const float pr = __expf(z - s_red[8]);
    float s = pr;
    #pragma unroll
    for (int off = 32; off > 0; off >>= 1)
        s += __shfl_xor(s, off, 64);
    if (lane == 0) s_red[wid] = s;
    __syncthreads();
    if (t < 64) {
        float ss = (t < 8) ? s_red[t] : 0.f;
        #pragma unroll
        for (int off = 4; off > 0; off >>= 1)
            ss += __shfl_xor(ss, off, 64);
        if (t == 0) s_red[9] = ss;
    }
    __syncthreads();
    const float attn = pr * (1.0f / s_red[9]);
    attn_out[(size_t)bqi * 512 + t] = attn;
    attnb[(size_t)bqi * 512 + t] = (short)f2bf(attn);
}

// ---------------------------------------------------------------------------
// PV GEMM: outh[b][128][1024] = attnb[b][128][512] @ valT[b][1024][512]^T
// 128m x 64n tile, K=512 (8 steps); grid b*16+nt = 64 blocks
__global__ __launch_bounds__(256) void pv_gemm(
    const short* __restrict__ attnb, const short* __restrict__ valT,
    float* __restrict__ outh)
{
    __shared__ short ldsA[2][128][64];
    __shared__ short ldsB[2][64][64];
    const int t = threadIdx.x, bx = blockIdx.x;
    const int b = bx >> 4, nt = bx & 15;
    const int n0 = nt * 64;
    const short* A = attnb + (size_t)b * 128 * 512;                    // [128][512]
    const short* B = valT + (size_t)b * 1024 * 512 + (size_t)n0 * 512; // [64][512] tile

    f32x4 acc[4][2];
    #pragma unroll
    for (int i = 0; i < 4; ++i)
        #pragma unroll
        for (int j = 0; j < 2; ++j) acc[i][j] = f32x4{0.f, 0.f, 0.f, 0.f};

    const int lane = t & 63, wid = t >> 6;
    const int wr = wid >> 1, wc = wid & 1;
    const int fr = lane & 15, fko = (lane >> 4) * 16;

    #define STAGE_PV(buf, k0) do {                                              \
        _Pragma("unroll")                                                       \
        for (int it = 0; it < 4; ++it) {                                        \
            const int idx = it * 256 + t;                                       \
            const int row = idx >> 3, c16 = idx & 7;                            \
            const int sc = c16 ^ (row & 7);                                     \
            GLD16(A + (size_t)row * 512 + (k0) + sc * 8,                        \
                  &ldsA[buf][0][0] + idx * 8);                                  \
        }                                                                       \
        _Pragma("unroll")                                                       \
        for (int it = 0; it < 2; ++it) {                                        \
            const int idx = it * 256 + t;                                       \
            const int row = idx >> 3, c16 = idx & 7;                            \
            const int sc = c16 ^ (row & 7);                                     \
            GLD16(B + (size_t)row * 512 + (k0) + sc * 8,                        \
                  &ldsB[buf][0][0] + idx * 8);                                  \
        }                                                                       \
    } while (0)

    #define COMPUTE_PV(buf) do {                                                \
        _Pragma("unroll")                                                       \
        for (int kk = 0; kk < 2; ++kk) {                                        \
            s16x8 af[4], bfv[2];                                                \
            _Pragma("unroll")                                                   \
            for (int i = 0; i < 4; ++i) {                                       \
                const int rowA = wr * 64 + i * 16 + fr;                         \
                int offA = rowA * 128 + kk * 64 + fko; offA ^= (rowA & 7) << 4; \
                af[i] = *(const s16x8*)((const char*)&ldsA[buf][0][0] + offA);  \
            }                                                                   \
            _Pragma("unroll")                                                   \
            for (int ni = 0; ni < 2; ++ni) {                                    \
                const int rowB = wc * 32 + ni * 16 + fr;                        \
                int offB = rowB * 128 + kk * 64 + fko; offB ^= (rowB & 7) << 4; \
                bfv[ni] = *(const s16x8*)((const char*)&ldsB[buf][0][0] + offB);\
            }                                                                   \
            _Pragma("unroll")                                                   \
            for (int mi = 0; mi < 4; ++mi)                                      \
                _Pragma("unroll")                                               \
                for (int ni = 0; ni < 2; ++ni)                                  \
                    acc[mi][ni] = __builtin_amdgcn_mfma_f32_16x16x32_bf16(      \
                                      af[mi], bfv[ni], acc[mi][ni], 0, 0, 0);   \
        }                                                                       \
    } while (0)

    STAGE_PV(0, 0);
    __syncthreads();
    int cur = 0;
    for (int s = 0; s < 7; ++s) {
        STAGE_PV(cur ^ 1, (s + 1) * 64);
        COMPUTE_PV(cur);
        __syncthreads();
        cur ^= 1;
    }
    COMPUTE_PV(cur);

    const int row0 = (lane >> 4) * 4;
    #pragma unroll
    for (int ni = 0; ni < 2; ++ni) {
        const int n = n0 + wc * 32 + ni * 16 + fr;
        #pragma unroll
        for (int mi = 0; mi < 4; ++mi) {
            const int m = wr * 64 + mi * 16 + row0;
            #pragma unroll
            for (int j = 0; j < 4; ++j)
                outh[(size_t)(b * 128 + m + j) * 1024 + n] = acc[mi][ni][j];
        }
    }
    #undef STAGE_PV
    #undef COMPUTE_PV
}

extern "C" void kernel_launch(void* const* d_in, const int* in_sizes, int n_in,
                              void* d_out, int out_size, void* d_ws, size_t ws_size,
                              hipStream_t stream)
{
    const float* query = (const float*)d_in[0];
    const float* key   = (const float*)d_in[1];
    const float* value = (const float*)d_in[2];
    const float* Wq    = (const float*)d_in[3];
    const float* bq    = (const float*)d_in[4];
    const float* Wk    = (const float*)d_in[5];
    const float* v     = (const float*)d_in[6];
    float* out = (float*)d_out;

    // workspace layout (40 MB of 256 MB):
    char* w = (char*)d_ws;
    float* ws_Ea  = (float*)w;                            // 2 MB
    float* ws_EbT = (float*)(w + (2u << 20));             // 8 MB
    short* Qb     = (short*)(w + (10u << 20));            // 1 MB
    short* Kb     = (short*)(w + (11u << 20));            // 4 MB
    short* WqT    = (short*)(w + (15u << 20));            // 2 MB
    short* WkT    = (short*)(w + (17u << 20));            // 2 MB
    short* valT   = (short*)(w + (19u << 20));            // 4 MB
    short* attnb  = (short*)(w + (23u << 20));            // 0.5 MB
    float* part   = (float*)(w + (24u << 20));            // 16 MB

    float* out_h    = out;                                // [512][1024]
    float* out_attn = out + (size_t)NB * NTQ * NH;        // [512][512]

    prep_kernel   <<<dim3(1664), dim3(256), 0, stream>>>(query, key, Wq, Wk, value,
                                                         Qb, Kb, WqT, WkT, valT);
    mm_kernel     <<<dim3(320),  dim3(256), 0, stream>>>(Qb, Kb, WqT, WkT, bq, ws_Ea, ws_EbT);
    scores_partial<<<dim3(1024), dim3(512), 0, stream>>>(ws_EbT, ws_Ea, v, part);
    softmax_kernel<<<dim3(512),  dim3(512), 0, stream>>>(part, out_attn, attnb);
    pv_gemm       <<<dim3(64),   dim3(256), 0, stream>>>(attnb, valT, out_h);
}